// Round 14
// baseline (608.612 us; speedup 1.0000x reference)
//
#include <hip/hip_runtime.h>

#define B_     8
#define N_     2048
#define J_     1024
#define QD_    1024
#define CD_    768
#define H_     16
#define D_     64
#define INNER_ 1024

typedef __attribute__((ext_vector_type(8)))  __bf16 bf16x8;
typedef __attribute__((ext_vector_type(4)))  __bf16 bf16x4;
typedef __attribute__((ext_vector_type(4)))  float  f32x4;
typedef __attribute__((ext_vector_type(16))) float  f32x16;
typedef __attribute__((ext_vector_type(2)))  unsigned uint2v;

__device__ __forceinline__ __bf16 to_bf16(float f) { return (__bf16)f; }

__device__ __forceinline__ unsigned pack2(float lo, float hi) {
    union { __bf16 h; unsigned short u; } a, b;
    a.h = (__bf16)lo; b.h = (__bf16)hi;
    return (unsigned)a.u | ((unsigned)b.u << 16);
}

// ---------------- fused aux: fp32->bf16 converts + all 4 weight transposes ----------------
#define NCVT_BLK 22528   // (8*2048*1024 + 8*1024*768)/4/256

__global__ __launch_bounds__(256)
void aux_all(const float* __restrict__ x, const float* __restrict__ ctx,
             __bf16* __restrict__ xb, __bf16* __restrict__ cb,
             const float* __restrict__ Wq, const float* __restrict__ Wk,
             const float* __restrict__ Wv, const float* __restrict__ Wo,
             __bf16* __restrict__ wqt, __bf16* __restrict__ wkt,
             __bf16* __restrict__ wvt, __bf16* __restrict__ wot, float sq)
{
    __shared__ float tile[32][33];
    const int blk = blockIdx.x;
    if (blk < NCVT_BLK) {
        const int nx = (B_ * N_ * QD_) / 4;
        const int nc = (B_ * J_ * CD_) / 4;
        int i = blk * 256 + threadIdx.x;
        if (i < nx) {
            float4 v = ((const float4*)x)[i];
            bf16x4 o;
            o[0] = (__bf16)v.x; o[1] = (__bf16)v.y; o[2] = (__bf16)v.z; o[3] = (__bf16)v.w;
            ((bf16x4*)xb)[i] = o;
        } else if (i < nx + nc) {
            float4 v = ((const float4*)ctx)[i - nx];
            bf16x4 o;
            o[0] = (__bf16)v.x; o[1] = (__bf16)v.y; o[2] = (__bf16)v.z; o[3] = (__bf16)v.w;
            ((bf16x4*)cb)[i - nx] = o;
        }
        return;
    }
    const int tb = blk - NCVT_BLK;           // 0..4095
    const int z  = tb >> 10;
    const int k0 = ((tb >> 5) & 31) * 32;
    const int n0 = (tb & 31) * 32;
    const float* W;  __bf16* Wt;  int K;  float scale = 1.f;
    if (z == 0)      { W = Wq; Wt = wqt; K = QD_;   scale = sq; }
    else if (z == 1) { W = Wk; Wt = wkt; K = CD_; }
    else if (z == 2) { W = Wv; Wt = wvt; K = CD_; }
    else             { W = Wo; Wt = wot; K = INNER_; }
    if (k0 >= K) return;
    const int N = 1024;
    const int tx = threadIdx.x & 31;
    const int ty = threadIdx.x >> 5;
#pragma unroll
    for (int r = 0; r < 32; r += 8)
        tile[ty + r][tx] = W[(size_t)(k0 + ty + r) * N + n0 + tx];
    __syncthreads();
#pragma unroll
    for (int r = 0; r < 32; r += 8)
        Wt[(size_t)(n0 + ty + r) * K + k0 + tx] = to_bf16(tile[tx][ty + r] * scale);
}

// ================ 256x256 8-wave pipelined GEMM core (R10 schedule, verified) ==========
template<int FINAL, int KDIM>
__device__ __forceinline__
void core8(const __bf16* __restrict__ A, const __bf16* __restrict__ Bt,
           __bf16* __restrict__ Cb, __bf16* __restrict__ Cb2, float* __restrict__ Cf,
           const float* __restrict__ bias, int N, int work,
           __bf16 (&sA)[2][16384], __bf16 (&sB)[2][16384])
{
    constexpr int NIT = KDIM / 64;

    const int tid = threadIdx.x;
    const int wid = tid >> 6;
    const int l   = tid & 63;
    const int lo  = l & 15, hi = (l >> 4) & 3;

    const int gn = N >> 8;
    const int m0 = (work / gn) * 256;
    const int n0 = (work % gn) * 256;

    const int wm  = (wid >> 2) * 128, wn = (wid & 3) * 64;
    const int wmr = (wid >> 2) * 8,   bnr = (wid & 3) * 4;

    int rOff[2], cOff[2], dOff[2];
#pragma unroll
    for (int n = 0; n < 2; ++n) {
        const int s = n * 8 + wid;
        rOff[n] = (s >> 1) * 16 + (l >> 2);
        cOff[n] = (s & 1) * 32 + (((l & 3) * 8) ^ (((l >> 5) & 1) * 16));
        dOff[n] = n * 4096 + wid * 512;
    }

    const int inner = lo * 32 + ((hi * 8) ^ ((lo >> 3) * 16));

    f32x4 acc[8][4] = {};
    bf16x8 af[4][2], bfr[4][2];

#define STAGE8(nb, h, kt) do { \
    _Pragma("unroll") \
    for (int n = 0; n < 2; ++n) { \
        const __bf16* gp = ((h) < 2 ? A + (size_t)(m0 + ((h) & 1) * 128 + rOff[n]) * KDIM \
                                    : Bt + (size_t)(n0 + ((h) & 1) * 128 + rOff[n]) * KDIM) \
                           + (kt) + cOff[n]; \
        __bf16* dp = ((h) < 2 ? &sA[nb][((h) & 1) * 8192 + dOff[n]] \
                              : &sB[nb][((h) & 1) * 8192 + dOff[n]]); \
        __builtin_amdgcn_global_load_lds((const __attribute__((address_space(1))) void*)gp, \
                                         (__attribute__((address_space(3))) void*)dp, 16, 0, 0); \
    } } while (0)

#define RD_A(x0, cnt, nb) do { \
    _Pragma("unroll") \
    for (int x = 0; x < (cnt); ++x) \
        _Pragma("unroll") \
        for (int kk = 0; kk < 2; ++kk) \
            af[x][kk] = *(const bf16x8*)&sA[nb][((wmr + (x0) + x) * 2 + kk) * 512 + inner]; \
    } while (0)

#define RD_B(j0, cnt, nb) do { \
    _Pragma("unroll") \
    for (int j = 0; j < (cnt); ++j) \
        _Pragma("unroll") \
        for (int kk = 0; kk < 2; ++kk) \
            bfr[(j0) + j][kk] = *(const bf16x8*)&sB[nb][((bnr + (j0) + j) * 2 + kk) * 512 + inner]; \
    } while (0)

#define MMQ(mh, nh) do { \
    __builtin_amdgcn_s_setprio(1); \
    _Pragma("unroll") \
    for (int x = 0; x < 4; ++x) \
        _Pragma("unroll") \
        for (int j = 0; j < 2; ++j) \
            _Pragma("unroll") \
            for (int kk = 0; kk < 2; ++kk) \
                acc[(mh) * 4 + x][(nh) * 2 + j] = __builtin_amdgcn_mfma_f32_16x16x32_bf16( \
                    af[x][kk], bfr[(nh) * 2 + j][kk], acc[(mh) * 4 + x][(nh) * 2 + j], 0, 0, 0); \
    __builtin_amdgcn_s_setprio(0); \
    } while (0)

#define BARR() do { __builtin_amdgcn_s_barrier(); \
    asm volatile("" ::: "memory"); __builtin_amdgcn_sched_barrier(0); } while (0)

#pragma unroll
    for (int h = 0; h < 4; ++h) STAGE8(0, h, 0);

    for (int it = 0; it < NIT; ++it) {
        const int nb = it & 1, nbn = nb ^ 1;
        const int ktn = (it + 1) * 64;
        const bool notlast = (it < NIT - 1);

        if (notlast) STAGE8(nbn, 0, ktn);
        if (notlast) asm volatile("s_waitcnt vmcnt(2)" ::: "memory");
        else         asm volatile("s_waitcnt vmcnt(0)" ::: "memory");
        BARR();
        RD_A(0, 4, nb); RD_B(0, 2, nb);
        MMQ(0, 0);
        BARR();
        if (notlast) STAGE8(nbn, 1, ktn);
        BARR();
        RD_B(2, 2, nb);
        MMQ(0, 1);
        BARR();
        if (notlast) STAGE8(nbn, 2, ktn);
        BARR();
        RD_A(4, 4, nb);
        MMQ(1, 0);
        BARR();
        if (notlast) STAGE8(nbn, 3, ktn);
        BARR();
        MMQ(1, 1);
        BARR();
    }
#undef STAGE8
#undef RD_A
#undef RD_B
#undef MMQ
#undef BARR

#pragma unroll
    for (int i = 0; i < 8; ++i) {
        const int row = m0 + wm + i * 16 + hi * 4;
#pragma unroll
        for (int j = 0; j < 4; ++j) {
            const int col = n0 + wn + j * 16 + lo;
            if (FINAL == 3) {
                if (col < 1024) {
#pragma unroll
                    for (int r = 0; r < 4; ++r)
                        Cb[(size_t)(row + r) * 1024 + col] = to_bf16(acc[i][j][r]);
                } else {
                    const int c2 = col - 1024;
                    const int head = c2 >> 6, d = c2 & 63;
                    const int bb = row >> 10, jj = row & 1023;
                    bf16x4 v4;
#pragma unroll
                    for (int r = 0; r < 4; ++r) v4[r] = to_bf16(acc[i][j][r]);
                    *(bf16x4*)&Cb2[(((size_t)(bb * 16 + head)) * 64 + d) * (size_t)J_ + jj] = v4;
                }
            } else {
#pragma unroll
                for (int r = 0; r < 4; ++r) {
                    if (FINAL == 1) Cf[(size_t)(row + r) * N + col] = acc[i][j][r] + bias[col];
                    else            Cb[(size_t)(row + r) * N + col] = to_bf16(acc[i][j][r]);
                }
            }
        }
    }
}

// Merged Q-proj + KV-proj (XCD-chunked halves, 2 blocks/CU co-residency)
__global__ __launch_bounds__(512, 2)
void gemm_qkv(const __bf16* __restrict__ xb, const __bf16* __restrict__ wqt, __bf16* __restrict__ Qb,
              const __bf16* __restrict__ cb, const __bf16* __restrict__ wkt,
              __bf16* __restrict__ Kb, __bf16* __restrict__ Vt)
{
    __shared__ __bf16 sA[2][16384];
    __shared__ __bf16 sB[2][16384];
    const int blk = blockIdx.x;
    if (blk < 256) {
        const int work = (blk & 7) * 32 + (blk >> 3);
        core8<0, QD_>(xb, wqt, Qb, nullptr, nullptr, nullptr, INNER_, work, sA, sB);
    } else {
        const int hb = blk - 256;
        const int work = (hb & 7) * 32 + (hb >> 3);
        core8<3, CD_>(cb, wkt, Kb, Vt, nullptr, nullptr, 2 * INNER_, work, sA, sB);
    }
}

// O-projection: fp32 + bias, XCD-chunked.
__global__ __launch_bounds__(512, 2)
void gemm_o(const __bf16* __restrict__ Ob, const __bf16* __restrict__ wot,
            float* __restrict__ out, const float* __restrict__ bias)
{
    __shared__ __bf16 sA[2][16384];
    __shared__ __bf16 sB[2][16384];
    const int blk = blockIdx.x;
    const int work = (blk & 7) * 32 + (blk >> 3);
    core8<1, INNER_>(Ob, wot, nullptr, nullptr, out, bias, QD_, work, sA, sB);
}

// ---------------- attention: R13 structure + 4-way accO chain split ----------------
// All 16 PV MFMAs per tile previously fed 2 register chains (accO[dt]); with ~32cyc
// MFMA latency vs ~8cyc issue that leaves unhidden stalls. Split by k2-parity into
// accO[k2][dt] (4 independent chains, statically indexed), elementwise-summed in
// the epilogue. Numerics: each j contributes to exactly one chain -> reassociation only.
#define SEGE 544

__global__ __launch_bounds__(256, 4)
void attn2(const __bf16* __restrict__ Qb, const __bf16* __restrict__ Kb,
           const __bf16* __restrict__ Vt, __bf16* __restrict__ Ob)
{
    __shared__ __bf16 sK[2][8 * SEGE];
    __shared__ __bf16 sV[2][8 * SEGE];

    const int tid = threadIdx.x;
    const int wid = tid >> 6;
    const int l   = tid & 63;
    const int lq  = l & 31;
    const int hi  = l >> 5;

    const int blk  = blockIdx.x;
    const int work = (blk & 7) * 256 + (blk >> 3);
    const int qt = work & 15;
    const int h  = (work >> 4) & 15;
    const int b  = work >> 8;
    const int bh = b * H_ + h;

    bf16x8 qf[4];
    {
        const __bf16* qp = Qb + ((size_t)b * N_ + qt * 128 + wid * 32 + lq) * INNER_ + h * D_;
#pragma unroll
        for (int kc = 0; kc < 4; ++kc)
            qf[kc] = *(const bf16x8*)(qp + kc * 16 + hi * 8);
    }

    f32x16 accO[2][2] = {};        // [k2-parity][d-tile] : 4 independent MFMA chains
    float lsum = 0.f;

    const int srow = l >> 3, schk = l & 7;
    const __bf16* ksrc = Kb + ((size_t)b * J_ + wid * 8 + srow) * INNER_ + h * D_ + ((schk ^ srow) * 8);
    const __bf16* vsrc = Vt + ((size_t)bh * D_ + wid * 8 + srow) * J_ + ((schk ^ srow) * 8);

#define STAGE_T(bb, t) do { \
    _Pragma("unroll") \
    for (int c = 0; c < 2; ++c) { \
        __builtin_amdgcn_global_load_lds((const __attribute__((address_space(1))) void*)(ksrc + ((size_t)(t) * 64 + c * 32) * INNER_), \
            (__attribute__((address_space(3))) void*)(&sK[bb][(c * 4 + wid) * SEGE]), 16, 0, 0); \
        __builtin_amdgcn_global_load_lds((const __attribute__((address_space(1))) void*)(vsrc + (size_t)(c) * 32 * J_ + (t) * 64), \
            (__attribute__((address_space(3))) void*)(&sV[bb][(c * 4 + wid) * SEGE]), 16, 0, 0); \
    } } while (0)

    STAGE_T(0, 0);
    __syncthreads();

    for (int t = 0; t < J_ / 64; ++t) {
        const int bb = t & 1;
        if (t < J_ / 64 - 1) STAGE_T(bb ^ 1, t + 1);

        const __bf16* Ks = sK[bb];
        const __bf16* Vs = sV[bb];

#pragma unroll
        for (int jsub = 0; jsub < 2; ++jsub) {
            bf16x8 kf[4], vf[2][2];
            const int ksg = (jsub * 4 + (lq >> 3)) * SEGE + (lq & 7) * 64;
#pragma unroll
            for (int kc = 0; kc < 4; ++kc)
                kf[kc] = *(const bf16x8*)&Ks[ksg + (((kc * 2 + hi) ^ (lq & 7)) * 8)];
#pragma unroll
            for (int dt = 0; dt < 2; ++dt) {
                const int vsg = (dt * 4 + (lq >> 3)) * SEGE + (lq & 7) * 64;
#pragma unroll
                for (int k2 = 0; k2 < 2; ++k2)
                    vf[dt][k2] = *(const bf16x8*)&Vs[vsg + ((((jsub * 2 + k2) * 2 + hi) ^ (lq & 7)) * 8)];
            }

            f32x16 s = {};
            __builtin_amdgcn_s_setprio(1);
#pragma unroll
            for (int kc = 0; kc < 4; ++kc)
                s = __builtin_amdgcn_mfma_f32_32x32x16_bf16(kf[kc], qf[kc], s, 0, 0, 0);
            __builtin_amdgcn_s_setprio(0);

            float p[16];
#pragma unroll
            for (int r = 0; r < 16; ++r)
                p[r] = __builtin_amdgcn_exp2f(s[r]);
            {
                float t0 = (p[0] + p[1]) + (p[2] + p[3]);
                float t1 = (p[4] + p[5]) + (p[6] + p[7]);
                float t2 = (p[8] + p[9]) + (p[10] + p[11]);
                float t3 = (p[12] + p[13]) + (p[14] + p[15]);
                lsum += (t0 + t1) + (t2 + t3);
            }

#pragma unroll
            for (int k2 = 0; k2 < 2; ++k2) {
                unsigned a0 = pack2(p[k2 * 8 + 0], p[k2 * 8 + 1]);
                unsigned a1 = pack2(p[k2 * 8 + 2], p[k2 * 8 + 3]);
                unsigned b0 = pack2(p[k2 * 8 + 4], p[k2 * 8 + 5]);
                unsigned b1 = pack2(p[k2 * 8 + 6], p[k2 * 8 + 7]);
                uint2v r0 = __builtin_amdgcn_permlane32_swap(a0, b0, false, false);
                uint2v r1 = __builtin_amdgcn_permlane32_swap(a1, b1, false, false);
                union { unsigned u[4]; bf16x8 v; } pu;
                pu.u[0] = r0[0];
                pu.u[1] = r1[0];
                pu.u[2] = r0[1];
                pu.u[3] = r1[1];
                __builtin_amdgcn_s_setprio(1);
#pragma unroll
                for (int dt = 0; dt < 2; ++dt)
                    accO[k2][dt] = __builtin_amdgcn_mfma_f32_32x32x16_bf16(vf[dt][k2], pu.v, accO[k2][dt], 0, 0, 0);
                __builtin_amdgcn_s_setprio(0);
            }
        }
        __syncthreads();
    }
#undef STAGE_T

    {
        float lt = lsum + __shfl_xor(lsum, 32);
        float inv = 1.f / lt;
        __bf16* op = Ob + ((size_t)b * N_ + qt * 128 + wid * 32 + lq) * INNER_ + h * D_;
#pragma unroll
        for (int dt = 0; dt < 2; ++dt) {
            f32x16 am = accO[0][dt] + accO[1][dt];   // merge the k2-parity chains
#pragma unroll
            for (int g = 0; g < 4; ++g) {
                bf16x4 v4;
#pragma unroll
                for (int e = 0; e < 4; ++e) v4[e] = to_bf16(am[g * 4 + e] * inv);
                *(bf16x4*)&op[dt * 32 + g * 8 + hi * 4] = v4;
            }
        }
    }
}

// ---------------- host ----------------
extern "C" void kernel_launch(void* const* d_in, const int* in_sizes, int n_in,
                              void* d_out, int out_size, void* d_ws, size_t ws_size,
                              hipStream_t stream)
{
    const float* x   = (const float*)d_in[0];
    const float* ctx = (const float*)d_in[1];
    const float* Wq  = (const float*)d_in[2];
    const float* Wk  = (const float*)d_in[3];
    const float* Wv  = (const float*)d_in[4];
    const float* Wo  = (const float*)d_in[5];
    const float* bo  = (const float*)d_in[6];
    float* out = (float*)d_out;

    char* w = (char*)d_ws;
    auto take = [&](size_t bytes) { char* p = w; w += bytes; return p; };
    __bf16* xb  = (__bf16*)take((size_t)B_ * N_ * QD_ * 2);
    __bf16* cb  = (__bf16*)take((size_t)B_ * J_ * CD_ * 2);
    __bf16* wqt = (__bf16*)take((size_t)QD_ * INNER_ * 2);
    __bf16* wkt = (__bf16*)take((size_t)CD_ * INNER_ * 2);   // wkt+wvt adjacent
    __bf16* wvt = (__bf16*)take((size_t)CD_ * INNER_ * 2);
    __bf16* wot = (__bf16*)take((size_t)INNER_ * QD_ * 2);
    __bf16* Qb  = (__bf16*)take((size_t)B_ * N_ * INNER_ * 2);
    __bf16* Kb  = (__bf16*)take((size_t)B_ * J_ * INNER_ * 2);
    __bf16* Vt  = (__bf16*)take((size_t)B_ * J_ * INNER_ * 2);
    __bf16* Ob  = xb;

    const float SCALE_Q = 0.125f * 1.44269504088896f;

    aux_all<<<NCVT_BLK + 4096, 256, 0, stream>>>(x, ctx, xb, cb,
                                                 Wq, Wk, Wv, Wo,
                                                 wqt, wkt, wvt, wot, SCALE_Q);

    gemm_qkv<<<512, 512, 0, stream>>>(xb, wqt, Qb, cb, wkt, Kb, Vt);

    attn2<<<(N_ / 128) * H_ * B_, 256, 0, stream>>>(Qb, Kb, Vt, Ob);

    gemm_o<<<256, 512, 0, stream>>>(Ob, wot, out, bo);
}

// Round 15
// 242.912 us; speedup vs baseline: 2.5055x; 2.5055x over previous
//
#include <hip/hip_runtime.h>

#define B_     8
#define N_     2048
#define J_     1024
#define QD_    1024
#define CD_    768
#define H_     16
#define D_     64
#define INNER_ 1024

typedef __attribute__((ext_vector_type(8)))  __bf16 bf16x8;
typedef __attribute__((ext_vector_type(4)))  __bf16 bf16x4;
typedef __attribute__((ext_vector_type(4)))  float  f32x4;
typedef __attribute__((ext_vector_type(16))) float  f32x16;
typedef __attribute__((ext_vector_type(2)))  unsigned uint2v;

__device__ __forceinline__ __bf16 to_bf16(float f) { return (__bf16)f; }

__device__ __forceinline__ unsigned pack2(float lo, float hi) {
    union { __bf16 h; unsigned short u; } a, b;
    a.h = (__bf16)lo; b.h = (__bf16)hi;
    return (unsigned)a.u | ((unsigned)b.u << 16);
}

// ---------------- fused aux: fp32->bf16 converts + all 4 weight transposes ----------------
#define NCVT_BLK 22528   // (8*2048*1024 + 8*1024*768)/4/256

__global__ __launch_bounds__(256)
void aux_all(const float* __restrict__ x, const float* __restrict__ ctx,
             __bf16* __restrict__ xb, __bf16* __restrict__ cb,
             const float* __restrict__ Wq, const float* __restrict__ Wk,
             const float* __restrict__ Wv, const float* __restrict__ Wo,
             __bf16* __restrict__ wqt, __bf16* __restrict__ wkt,
             __bf16* __restrict__ wvt, __bf16* __restrict__ wot, float sq)
{
    __shared__ float tile[32][33];
    const int blk = blockIdx.x;
    if (blk < NCVT_BLK) {
        const int nx = (B_ * N_ * QD_) / 4;
        const int nc = (B_ * J_ * CD_) / 4;
        int i = blk * 256 + threadIdx.x;
        if (i < nx) {
            float4 v = ((const float4*)x)[i];
            bf16x4 o;
            o[0] = (__bf16)v.x; o[1] = (__bf16)v.y; o[2] = (__bf16)v.z; o[3] = (__bf16)v.w;
            ((bf16x4*)xb)[i] = o;
        } else if (i < nx + nc) {
            float4 v = ((const float4*)ctx)[i - nx];
            bf16x4 o;
            o[0] = (__bf16)v.x; o[1] = (__bf16)v.y; o[2] = (__bf16)v.z; o[3] = (__bf16)v.w;
            ((bf16x4*)cb)[i - nx] = o;
        }
        return;
    }
    const int tb = blk - NCVT_BLK;           // 0..4095
    const int z  = tb >> 10;
    const int k0 = ((tb >> 5) & 31) * 32;
    const int n0 = (tb & 31) * 32;
    const float* W;  __bf16* Wt;  int K;  float scale = 1.f;
    if (z == 0)      { W = Wq; Wt = wqt; K = QD_;   scale = sq; }
    else if (z == 1) { W = Wk; Wt = wkt; K = CD_; }
    else if (z == 2) { W = Wv; Wt = wvt; K = CD_; }
    else             { W = Wo; Wt = wot; K = INNER_; }
    if (k0 >= K) return;
    const int N = 1024;
    const int tx = threadIdx.x & 31;
    const int ty = threadIdx.x >> 5;
#pragma unroll
    for (int r = 0; r < 32; r += 8)
        tile[ty + r][tx] = W[(size_t)(k0 + ty + r) * N + n0 + tx];
    __syncthreads();
#pragma unroll
    for (int r = 0; r < 32; r += 8)
        Wt[(size_t)(n0 + ty + r) * K + k0 + tx] = to_bf16(tile[tx][ty + r] * scale);
}

// ================ 256x256 8-wave pipelined GEMM core (R10 schedule, verified) ==========
template<int FINAL, int KDIM>
__device__ __forceinline__
void core8(const __bf16* __restrict__ A, const __bf16* __restrict__ Bt,
           __bf16* __restrict__ Cb, __bf16* __restrict__ Cb2, float* __restrict__ Cf,
           const float* __restrict__ bias, int N, int work,
           __bf16 (&sA)[2][16384], __bf16 (&sB)[2][16384])
{
    constexpr int NIT = KDIM / 64;

    const int tid = threadIdx.x;
    const int wid = tid >> 6;
    const int l   = tid & 63;
    const int lo  = l & 15, hi = (l >> 4) & 3;

    const int gn = N >> 8;
    const int m0 = (work / gn) * 256;
    const int n0 = (work % gn) * 256;

    const int wm  = (wid >> 2) * 128, wn = (wid & 3) * 64;
    const int wmr = (wid >> 2) * 8,   bnr = (wid & 3) * 4;

    int rOff[2], cOff[2], dOff[2];
#pragma unroll
    for (int n = 0; n < 2; ++n) {
        const int s = n * 8 + wid;
        rOff[n] = (s >> 1) * 16 + (l >> 2);
        cOff[n] = (s & 1) * 32 + (((l & 3) * 8) ^ (((l >> 5) & 1) * 16));
        dOff[n] = n * 4096 + wid * 512;
    }

    const int inner = lo * 32 + ((hi * 8) ^ ((lo >> 3) * 16));

    f32x4 acc[8][4] = {};
    bf16x8 af[4][2], bfr[4][2];

#define STAGE8(nb, h, kt) do { \
    _Pragma("unroll") \
    for (int n = 0; n < 2; ++n) { \
        const __bf16* gp = ((h) < 2 ? A + (size_t)(m0 + ((h) & 1) * 128 + rOff[n]) * KDIM \
                                    : Bt + (size_t)(n0 + ((h) & 1) * 128 + rOff[n]) * KDIM) \
                           + (kt) + cOff[n]; \
        __bf16* dp = ((h) < 2 ? &sA[nb][((h) & 1) * 8192 + dOff[n]] \
                              : &sB[nb][((h) & 1) * 8192 + dOff[n]]); \
        __builtin_amdgcn_global_load_lds((const __attribute__((address_space(1))) void*)gp, \
                                         (__attribute__((address_space(3))) void*)dp, 16, 0, 0); \
    } } while (0)

#define RD_A(x0, cnt, nb) do { \
    _Pragma("unroll") \
    for (int x = 0; x < (cnt); ++x) \
        _Pragma("unroll") \
        for (int kk = 0; kk < 2; ++kk) \
            af[x][kk] = *(const bf16x8*)&sA[nb][((wmr + (x0) + x) * 2 + kk) * 512 + inner]; \
    } while (0)

#define RD_B(j0, cnt, nb) do { \
    _Pragma("unroll") \
    for (int j = 0; j < (cnt); ++j) \
        _Pragma("unroll") \
        for (int kk = 0; kk < 2; ++kk) \
            bfr[(j0) + j][kk] = *(const bf16x8*)&sB[nb][((bnr + (j0) + j) * 2 + kk) * 512 + inner]; \
    } while (0)

#define MMQ(mh, nh) do { \
    __builtin_amdgcn_s_setprio(1); \
    _Pragma("unroll") \
    for (int x = 0; x < 4; ++x) \
        _Pragma("unroll") \
        for (int j = 0; j < 2; ++j) \
            _Pragma("unroll") \
            for (int kk = 0; kk < 2; ++kk) \
                acc[(mh) * 4 + x][(nh) * 2 + j] = __builtin_amdgcn_mfma_f32_16x16x32_bf16( \
                    af[x][kk], bfr[(nh) * 2 + j][kk], acc[(mh) * 4 + x][(nh) * 2 + j], 0, 0, 0); \
    __builtin_amdgcn_s_setprio(0); \
    } while (0)

#define BARR() do { __builtin_amdgcn_s_barrier(); \
    asm volatile("" ::: "memory"); __builtin_amdgcn_sched_barrier(0); } while (0)

#pragma unroll
    for (int h = 0; h < 4; ++h) STAGE8(0, h, 0);

    for (int it = 0; it < NIT; ++it) {
        const int nb = it & 1, nbn = nb ^ 1;
        const int ktn = (it + 1) * 64;
        const bool notlast = (it < NIT - 1);

        if (notlast) STAGE8(nbn, 0, ktn);
        if (notlast) asm volatile("s_waitcnt vmcnt(2)" ::: "memory");
        else         asm volatile("s_waitcnt vmcnt(0)" ::: "memory");
        BARR();
        RD_A(0, 4, nb); RD_B(0, 2, nb);
        MMQ(0, 0);
        BARR();
        if (notlast) STAGE8(nbn, 1, ktn);
        BARR();
        RD_B(2, 2, nb);
        MMQ(0, 1);
        BARR();
        if (notlast) STAGE8(nbn, 2, ktn);
        BARR();
        RD_A(4, 4, nb);
        MMQ(1, 0);
        BARR();
        if (notlast) STAGE8(nbn, 3, ktn);
        BARR();
        MMQ(1, 1);
        BARR();
    }
#undef STAGE8
#undef RD_A
#undef RD_B
#undef MMQ
#undef BARR

#pragma unroll
    for (int i = 0; i < 8; ++i) {
        const int row = m0 + wm + i * 16 + hi * 4;
#pragma unroll
        for (int j = 0; j < 4; ++j) {
            const int col = n0 + wn + j * 16 + lo;
            if (FINAL == 3) {
                if (col < 1024) {
#pragma unroll
                    for (int r = 0; r < 4; ++r)
                        Cb[(size_t)(row + r) * 1024 + col] = to_bf16(acc[i][j][r]);
                } else {
                    const int c2 = col - 1024;
                    const int head = c2 >> 6, d = c2 & 63;
                    const int bb = row >> 10, jj = row & 1023;
                    bf16x4 v4;
#pragma unroll
                    for (int r = 0; r < 4; ++r) v4[r] = to_bf16(acc[i][j][r]);
                    *(bf16x4*)&Cb2[(((size_t)(bb * 16 + head)) * 64 + d) * (size_t)J_ + jj] = v4;
                }
            } else {
#pragma unroll
                for (int r = 0; r < 4; ++r) {
                    if (FINAL == 1) Cf[(size_t)(row + r) * N + col] = acc[i][j][r] + bias[col];
                    else            Cb[(size_t)(row + r) * N + col] = to_bf16(acc[i][j][r]);
                }
            }
        }
    }
}

// Merged Q-proj + KV-proj (XCD-chunked halves, 2 blocks/CU co-residency)
__global__ __launch_bounds__(512, 2)
void gemm_qkv(const __bf16* __restrict__ xb, const __bf16* __restrict__ wqt, __bf16* __restrict__ Qb,
              const __bf16* __restrict__ cb, const __bf16* __restrict__ wkt,
              __bf16* __restrict__ Kb, __bf16* __restrict__ Vt)
{
    __shared__ __bf16 sA[2][16384];
    __shared__ __bf16 sB[2][16384];
    const int blk = blockIdx.x;
    if (blk < 256) {
        const int work = (blk & 7) * 32 + (blk >> 3);
        core8<0, QD_>(xb, wqt, Qb, nullptr, nullptr, nullptr, INNER_, work, sA, sB);
    } else {
        const int hb = blk - 256;
        const int work = (hb & 7) * 32 + (hb >> 3);
        core8<3, CD_>(cb, wkt, Kb, Vt, nullptr, nullptr, 2 * INNER_, work, sA, sB);
    }
}

// O-projection: fp32 + bias, XCD-chunked.
__global__ __launch_bounds__(512, 2)
void gemm_o(const __bf16* __restrict__ Ob, const __bf16* __restrict__ wot,
            float* __restrict__ out, const float* __restrict__ bias)
{
    __shared__ __bf16 sA[2][16384];
    __shared__ __bf16 sB[2][16384];
    const int blk = blockIdx.x;
    const int work = (blk & 7) * 32 + (blk >> 3);
    core8<1, INNER_>(Ob, wot, nullptr, nullptr, out, bias, QD_, work, sA, sB);
}

// ---------------- attention (reverted to R13-proven accO[2]; R14's [2][2] split
// spilled the accumulator to scratch — rule #20 + 128-VGPR cap at 4 blocks/CU) ----
#define SEGE 544

__global__ __launch_bounds__(256, 4)
void attn2(const __bf16* __restrict__ Qb, const __bf16* __restrict__ Kb,
           const __bf16* __restrict__ Vt, __bf16* __restrict__ Ob)
{
    __shared__ __bf16 sK[2][8 * SEGE];
    __shared__ __bf16 sV[2][8 * SEGE];

    const int tid = threadIdx.x;
    const int wid = tid >> 6;
    const int l   = tid & 63;
    const int lq  = l & 31;
    const int hi  = l >> 5;

    const int blk  = blockIdx.x;
    const int work = (blk & 7) * 256 + (blk >> 3);
    const int qt = work & 15;
    const int h  = (work >> 4) & 15;
    const int b  = work >> 8;
    const int bh = b * H_ + h;

    bf16x8 qf[4];
    {
        const __bf16* qp = Qb + ((size_t)b * N_ + qt * 128 + wid * 32 + lq) * INNER_ + h * D_;
#pragma unroll
        for (int kc = 0; kc < 4; ++kc)
            qf[kc] = *(const bf16x8*)(qp + kc * 16 + hi * 8);
    }

    f32x16 accO[2] = {};
    float lsum = 0.f;

    const int srow = l >> 3, schk = l & 7;
    const __bf16* ksrc = Kb + ((size_t)b * J_ + wid * 8 + srow) * INNER_ + h * D_ + ((schk ^ srow) * 8);
    const __bf16* vsrc = Vt + ((size_t)bh * D_ + wid * 8 + srow) * J_ + ((schk ^ srow) * 8);

#define STAGE_T(bb, t) do { \
    _Pragma("unroll") \
    for (int c = 0; c < 2; ++c) { \
        __builtin_amdgcn_global_load_lds((const __attribute__((address_space(1))) void*)(ksrc + ((size_t)(t) * 64 + c * 32) * INNER_), \
            (__attribute__((address_space(3))) void*)(&sK[bb][(c * 4 + wid) * SEGE]), 16, 0, 0); \
        __builtin_amdgcn_global_load_lds((const __attribute__((address_space(1))) void*)(vsrc + (size_t)(c) * 32 * J_ + (t) * 64), \
            (__attribute__((address_space(3))) void*)(&sV[bb][(c * 4 + wid) * SEGE]), 16, 0, 0); \
    } } while (0)

    STAGE_T(0, 0);
    __syncthreads();

    for (int t = 0; t < J_ / 64; ++t) {
        const int bb = t & 1;
        if (t < J_ / 64 - 1) STAGE_T(bb ^ 1, t + 1);

        const __bf16* Ks = sK[bb];
        const __bf16* Vs = sV[bb];

#pragma unroll
        for (int jsub = 0; jsub < 2; ++jsub) {
            bf16x8 kf[4], vf[2][2];
            const int ksg = (jsub * 4 + (lq >> 3)) * SEGE + (lq & 7) * 64;
#pragma unroll
            for (int kc = 0; kc < 4; ++kc)
                kf[kc] = *(const bf16x8*)&Ks[ksg + (((kc * 2 + hi) ^ (lq & 7)) * 8)];
#pragma unroll
            for (int dt = 0; dt < 2; ++dt) {
                const int vsg = (dt * 4 + (lq >> 3)) * SEGE + (lq & 7) * 64;
#pragma unroll
                for (int k2 = 0; k2 < 2; ++k2)
                    vf[dt][k2] = *(const bf16x8*)&Vs[vsg + ((((jsub * 2 + k2) * 2 + hi) ^ (lq & 7)) * 8)];
            }

            f32x16 s = {};
            __builtin_amdgcn_s_setprio(1);
#pragma unroll
            for (int kc = 0; kc < 4; ++kc)
                s = __builtin_amdgcn_mfma_f32_32x32x16_bf16(kf[kc], qf[kc], s, 0, 0, 0);
            __builtin_amdgcn_s_setprio(0);

            float p[16];
#pragma unroll
            for (int r = 0; r < 16; ++r)
                p[r] = __builtin_amdgcn_exp2f(s[r]);
            {
                float t0 = (p[0] + p[1]) + (p[2] + p[3]);
                float t1 = (p[4] + p[5]) + (p[6] + p[7]);
                float t2 = (p[8] + p[9]) + (p[10] + p[11]);
                float t3 = (p[12] + p[13]) + (p[14] + p[15]);
                lsum += (t0 + t1) + (t2 + t3);
            }

#pragma unroll
            for (int k2 = 0; k2 < 2; ++k2) {
                unsigned a0 = pack2(p[k2 * 8 + 0], p[k2 * 8 + 1]);
                unsigned a1 = pack2(p[k2 * 8 + 2], p[k2 * 8 + 3]);
                unsigned b0 = pack2(p[k2 * 8 + 4], p[k2 * 8 + 5]);
                unsigned b1 = pack2(p[k2 * 8 + 6], p[k2 * 8 + 7]);
                uint2v r0 = __builtin_amdgcn_permlane32_swap(a0, b0, false, false);
                uint2v r1 = __builtin_amdgcn_permlane32_swap(a1, b1, false, false);
                union { unsigned u[4]; bf16x8 v; } pu;
                pu.u[0] = r0[0];
                pu.u[1] = r1[0];
                pu.u[2] = r0[1];
                pu.u[3] = r1[1];
                __builtin_amdgcn_s_setprio(1);
#pragma unroll
                for (int dt = 0; dt < 2; ++dt)
                    accO[dt] = __builtin_amdgcn_mfma_f32_32x32x16_bf16(vf[dt][k2], pu.v, accO[dt], 0, 0, 0);
                __builtin_amdgcn_s_setprio(0);
            }
        }
        __syncthreads();
    }
#undef STAGE_T

    {
        float lt = lsum + __shfl_xor(lsum, 32);
        float inv = 1.f / lt;
        __bf16* op = Ob + ((size_t)b * N_ + qt * 128 + wid * 32 + lq) * INNER_ + h * D_;
#pragma unroll
        for (int dt = 0; dt < 2; ++dt)
#pragma unroll
            for (int g = 0; g < 4; ++g) {
                bf16x4 v4;
#pragma unroll
                for (int e = 0; e < 4; ++e) v4[e] = to_bf16(accO[dt][g * 4 + e] * inv);
                *(bf16x4*)&op[dt * 32 + g * 8 + hi * 4] = v4;
            }
    }
}

// ---------------- host ----------------
extern "C" void kernel_launch(void* const* d_in, const int* in_sizes, int n_in,
                              void* d_out, int out_size, void* d_ws, size_t ws_size,
                              hipStream_t stream)
{
    const float* x   = (const float*)d_in[0];
    const float* ctx = (const float*)d_in[1];
    const float* Wq  = (const float*)d_in[2];
    const float* Wk  = (const float*)d_in[3];
    const float* Wv  = (const float*)d_in[4];
    const float* Wo  = (const float*)d_in[5];
    const float* bo  = (const float*)d_in[6];
    float* out = (float*)d_out;

    char* w = (char*)d_ws;
    auto take = [&](size_t bytes) { char* p = w; w += bytes; return p; };
    __bf16* xb  = (__bf16*)take((size_t)B_ * N_ * QD_ * 2);
    __bf16* cb  = (__bf16*)take((size_t)B_ * J_ * CD_ * 2);
    __bf16* wqt = (__bf16*)take((size_t)QD_ * INNER_ * 2);
    __bf16* wkt = (__bf16*)take((size_t)CD_ * INNER_ * 2);   // wkt+wvt adjacent
    __bf16* wvt = (__bf16*)take((size_t)CD_ * INNER_ * 2);
    __bf16* wot = (__bf16*)take((size_t)INNER_ * QD_ * 2);
    __bf16* Qb  = (__bf16*)take((size_t)B_ * N_ * INNER_ * 2);
    __bf16* Kb  = (__bf16*)take((size_t)B_ * J_ * INNER_ * 2);
    __bf16* Vt  = (__bf16*)take((size_t)B_ * J_ * INNER_ * 2);
    __bf16* Ob  = xb;

    const float SCALE_Q = 0.125f * 1.44269504088896f;

    aux_all<<<NCVT_BLK + 4096, 256, 0, stream>>>(x, ctx, xb, cb,
                                                 Wq, Wk, Wv, Wo,
                                                 wqt, wkt, wvt, wot, SCALE_Q);

    gemm_qkv<<<512, 512, 0, stream>>>(xb, wqt, Qb, cb, wkt, Kb, Vt);

    attn2<<<(N_ / 128) * H_ * B_, 256, 0, stream>>>(Qb, Kb, Vt, Ob);

    gemm_o<<<256, 512, 0, stream>>>(Ob, wot, out, bo);
}

// Round 16
// 238.777 us; speedup vs baseline: 2.5489x; 1.0173x over previous
//
#include <hip/hip_runtime.h>

#define B_     8
#define N_     2048
#define J_     1024
#define QD_    1024
#define CD_    768
#define H_     16
#define D_     64
#define INNER_ 1024

typedef __attribute__((ext_vector_type(8)))  __bf16 bf16x8;
typedef __attribute__((ext_vector_type(4)))  __bf16 bf16x4;
typedef __attribute__((ext_vector_type(4)))  float  f32x4;
typedef __attribute__((ext_vector_type(16))) float  f32x16;
typedef __attribute__((ext_vector_type(2)))  unsigned uint2v;

__device__ __forceinline__ __bf16 to_bf16(float f) { return (__bf16)f; }

__device__ __forceinline__ unsigned pack2(float lo, float hi) {
    union { __bf16 h; unsigned short u; } a, b;
    a.h = (__bf16)lo; b.h = (__bf16)hi;
    return (unsigned)a.u | ((unsigned)b.u << 16);
}

// ---------------- fused aux: fp32->bf16 converts + all 4 weight transposes ----------------
#define NCVT_BLK 22528   // (8*2048*1024 + 8*1024*768)/4/256

__global__ __launch_bounds__(256)
void aux_all(const float* __restrict__ x, const float* __restrict__ ctx,
             __bf16* __restrict__ xb, __bf16* __restrict__ cb,
             const float* __restrict__ Wq, const float* __restrict__ Wk,
             const float* __restrict__ Wv, const float* __restrict__ Wo,
             __bf16* __restrict__ wqt, __bf16* __restrict__ wkt,
             __bf16* __restrict__ wvt, __bf16* __restrict__ wot, float sq)
{
    __shared__ float tile[32][33];
    const int blk = blockIdx.x;
    if (blk < NCVT_BLK) {
        const int nx = (B_ * N_ * QD_) / 4;
        const int nc = (B_ * J_ * CD_) / 4;
        int i = blk * 256 + threadIdx.x;
        if (i < nx) {
            float4 v = ((const float4*)x)[i];
            bf16x4 o;
            o[0] = (__bf16)v.x; o[1] = (__bf16)v.y; o[2] = (__bf16)v.z; o[3] = (__bf16)v.w;
            ((bf16x4*)xb)[i] = o;
        } else if (i < nx + nc) {
            float4 v = ((const float4*)ctx)[i - nx];
            bf16x4 o;
            o[0] = (__bf16)v.x; o[1] = (__bf16)v.y; o[2] = (__bf16)v.z; o[3] = (__bf16)v.w;
            ((bf16x4*)cb)[i - nx] = o;
        }
        return;
    }
    const int tb = blk - NCVT_BLK;           // 0..4095
    const int z  = tb >> 10;
    const int k0 = ((tb >> 5) & 31) * 32;
    const int n0 = (tb & 31) * 32;
    const float* W;  __bf16* Wt;  int K;  float scale = 1.f;
    if (z == 0)      { W = Wq; Wt = wqt; K = QD_;   scale = sq; }
    else if (z == 1) { W = Wk; Wt = wkt; K = CD_; }
    else if (z == 2) { W = Wv; Wt = wvt; K = CD_; }
    else             { W = Wo; Wt = wot; K = INNER_; }
    if (k0 >= K) return;
    const int N = 1024;
    const int tx = threadIdx.x & 31;
    const int ty = threadIdx.x >> 5;
#pragma unroll
    for (int r = 0; r < 32; r += 8)
        tile[ty + r][tx] = W[(size_t)(k0 + ty + r) * N + n0 + tx];
    __syncthreads();
#pragma unroll
    for (int r = 0; r < 32; r += 8)
        Wt[(size_t)(n0 + ty + r) * K + k0 + tx] = to_bf16(tile[tx][ty + r] * scale);
}

// ================ 256x256 8-wave pipelined GEMM core (R10 schedule, verified) ==========
template<int FINAL, int KDIM>
__device__ __forceinline__
void core8(const __bf16* __restrict__ A, const __bf16* __restrict__ Bt,
           __bf16* __restrict__ Cb, __bf16* __restrict__ Cb2, float* __restrict__ Cf,
           const float* __restrict__ bias, int N, int work,
           __bf16 (&sA)[2][16384], __bf16 (&sB)[2][16384])
{
    constexpr int NIT = KDIM / 64;

    const int tid = threadIdx.x;
    const int wid = tid >> 6;
    const int l   = tid & 63;
    const int lo  = l & 15, hi = (l >> 4) & 3;

    const int gn = N >> 8;
    const int m0 = (work / gn) * 256;
    const int n0 = (work % gn) * 256;

    const int wm  = (wid >> 2) * 128, wn = (wid & 3) * 64;
    const int wmr = (wid >> 2) * 8,   bnr = (wid & 3) * 4;

    int rOff[2], cOff[2], dOff[2];
#pragma unroll
    for (int n = 0; n < 2; ++n) {
        const int s = n * 8 + wid;
        rOff[n] = (s >> 1) * 16 + (l >> 2);
        cOff[n] = (s & 1) * 32 + (((l & 3) * 8) ^ (((l >> 5) & 1) * 16));
        dOff[n] = n * 4096 + wid * 512;
    }

    const int inner = lo * 32 + ((hi * 8) ^ ((lo >> 3) * 16));

    f32x4 acc[8][4] = {};
    bf16x8 af[4][2], bfr[4][2];

#define STAGE8(nb, h, kt) do { \
    _Pragma("unroll") \
    for (int n = 0; n < 2; ++n) { \
        const __bf16* gp = ((h) < 2 ? A + (size_t)(m0 + ((h) & 1) * 128 + rOff[n]) * KDIM \
                                    : Bt + (size_t)(n0 + ((h) & 1) * 128 + rOff[n]) * KDIM) \
                           + (kt) + cOff[n]; \
        __bf16* dp = ((h) < 2 ? &sA[nb][((h) & 1) * 8192 + dOff[n]] \
                              : &sB[nb][((h) & 1) * 8192 + dOff[n]]); \
        __builtin_amdgcn_global_load_lds((const __attribute__((address_space(1))) void*)gp, \
                                         (__attribute__((address_space(3))) void*)dp, 16, 0, 0); \
    } } while (0)

#define RD_A(x0, cnt, nb) do { \
    _Pragma("unroll") \
    for (int x = 0; x < (cnt); ++x) \
        _Pragma("unroll") \
        for (int kk = 0; kk < 2; ++kk) \
            af[x][kk] = *(const bf16x8*)&sA[nb][((wmr + (x0) + x) * 2 + kk) * 512 + inner]; \
    } while (0)

#define RD_B(j0, cnt, nb) do { \
    _Pragma("unroll") \
    for (int j = 0; j < (cnt); ++j) \
        _Pragma("unroll") \
        for (int kk = 0; kk < 2; ++kk) \
            bfr[(j0) + j][kk] = *(const bf16x8*)&sB[nb][((bnr + (j0) + j) * 2 + kk) * 512 + inner]; \
    } while (0)

#define MMQ(mh, nh) do { \
    __builtin_amdgcn_s_setprio(1); \
    _Pragma("unroll") \
    for (int x = 0; x < 4; ++x) \
        _Pragma("unroll") \
        for (int j = 0; j < 2; ++j) \
            _Pragma("unroll") \
            for (int kk = 0; kk < 2; ++kk) \
                acc[(mh) * 4 + x][(nh) * 2 + j] = __builtin_amdgcn_mfma_f32_16x16x32_bf16( \
                    af[x][kk], bfr[(nh) * 2 + j][kk], acc[(mh) * 4 + x][(nh) * 2 + j], 0, 0, 0); \
    __builtin_amdgcn_s_setprio(0); \
    } while (0)

#define BARR() do { __builtin_amdgcn_s_barrier(); \
    asm volatile("" ::: "memory"); __builtin_amdgcn_sched_barrier(0); } while (0)

#pragma unroll
    for (int h = 0; h < 4; ++h) STAGE8(0, h, 0);

    for (int it = 0; it < NIT; ++it) {
        const int nb = it & 1, nbn = nb ^ 1;
        const int ktn = (it + 1) * 64;
        const bool notlast = (it < NIT - 1);

        if (notlast) STAGE8(nbn, 0, ktn);
        if (notlast) asm volatile("s_waitcnt vmcnt(2)" ::: "memory");
        else         asm volatile("s_waitcnt vmcnt(0)" ::: "memory");
        BARR();
        RD_A(0, 4, nb); RD_B(0, 2, nb);
        MMQ(0, 0);
        BARR();
        if (notlast) STAGE8(nbn, 1, ktn);
        BARR();
        RD_B(2, 2, nb);
        MMQ(0, 1);
        BARR();
        if (notlast) STAGE8(nbn, 2, ktn);
        BARR();
        RD_A(4, 4, nb);
        MMQ(1, 0);
        BARR();
        if (notlast) STAGE8(nbn, 3, ktn);
        BARR();
        MMQ(1, 1);
        BARR();
    }
#undef STAGE8
#undef RD_A
#undef RD_B
#undef MMQ
#undef BARR

#pragma unroll
    for (int i = 0; i < 8; ++i) {
        const int row = m0 + wm + i * 16 + hi * 4;
#pragma unroll
        for (int j = 0; j < 4; ++j) {
            const int col = n0 + wn + j * 16 + lo;
            if (FINAL == 3) {
                if (col < 1024) {
#pragma unroll
                    for (int r = 0; r < 4; ++r)
                        Cb[(size_t)(row + r) * 1024 + col] = to_bf16(acc[i][j][r]);
                } else {
                    const int c2 = col - 1024;
                    const int head = c2 >> 6, d = c2 & 63;
                    const int bb = row >> 10, jj = row & 1023;
                    bf16x4 v4;
#pragma unroll
                    for (int r = 0; r < 4; ++r) v4[r] = to_bf16(acc[i][j][r]);
                    *(bf16x4*)&Cb2[(((size_t)(bb * 16 + head)) * 64 + d) * (size_t)J_ + jj] = v4;
                }
            } else {
#pragma unroll
                for (int r = 0; r < 4; ++r) {
                    if (FINAL == 1) Cf[(size_t)(row + r) * N + col] = acc[i][j][r] + bias[col];
                    else            Cb[(size_t)(row + r) * N + col] = to_bf16(acc[i][j][r]);
                }
            }
        }
    }
}

// Merged Q-proj + KV-proj (XCD-chunked halves, 2 blocks/CU co-residency)
__global__ __launch_bounds__(512, 2)
void gemm_qkv(const __bf16* __restrict__ xb, const __bf16* __restrict__ wqt, __bf16* __restrict__ Qb,
              const __bf16* __restrict__ cb, const __bf16* __restrict__ wkt,
              __bf16* __restrict__ Kb, __bf16* __restrict__ Vt)
{
    __shared__ __bf16 sA[2][16384];
    __shared__ __bf16 sB[2][16384];
    const int blk = blockIdx.x;
    if (blk < 256) {
        const int work = (blk & 7) * 32 + (blk >> 3);
        core8<0, QD_>(xb, wqt, Qb, nullptr, nullptr, nullptr, INNER_, work, sA, sB);
    } else {
        const int hb = blk - 256;
        const int work = (hb & 7) * 32 + (hb >> 3);
        core8<3, CD_>(cb, wkt, Kb, Vt, nullptr, nullptr, 2 * INNER_, work, sA, sB);
    }
}

// O-projection: fp32 + bias, XCD-chunked.
__global__ __launch_bounds__(512, 2)
void gemm_o(const __bf16* __restrict__ Ob, const __bf16* __restrict__ wot,
            float* __restrict__ out, const float* __restrict__ bias)
{
    __shared__ __bf16 sA[2][16384];
    __shared__ __bf16 sB[2][16384];
    const int blk = blockIdx.x;
    const int work = (blk & 7) * 32 + (blk >> 3);
    core8<1, INNER_>(Ob, wot, nullptr, nullptr, out, bias, QD_, work, sA, sB);
}

// ---------------- attention: 4-chain accumulator split at 3 blocks/CU ----------------
// R14's [2][2] split spilled under launch_bounds(256,4)'s 128-VGPR cap. Here:
// launch_bounds(256,3) -> 170-VGPR cap (R11 measured this occupancy at 98.5us),
// and the 4 chains are NAMED variables (acc0..acc3 = k2-parity x dt) so no array
// indexing can demote them (rule #20). Chains merged elementwise in the epilogue.
#define SEGE 544

__global__ __launch_bounds__(256, 3)
void attn2(const __bf16* __restrict__ Qb, const __bf16* __restrict__ Kb,
           const __bf16* __restrict__ Vt, __bf16* __restrict__ Ob)
{
    __shared__ __bf16 sK[2][8 * SEGE];
    __shared__ __bf16 sV[2][8 * SEGE];

    const int tid = threadIdx.x;
    const int wid = tid >> 6;
    const int l   = tid & 63;
    const int lq  = l & 31;
    const int hi  = l >> 5;

    const int blk  = blockIdx.x;
    const int work = (blk & 7) * 256 + (blk >> 3);
    const int qt = work & 15;
    const int h  = (work >> 4) & 15;
    const int b  = work >> 8;
    const int bh = b * H_ + h;

    bf16x8 qf[4];
    {
        const __bf16* qp = Qb + ((size_t)b * N_ + qt * 128 + wid * 32 + lq) * INNER_ + h * D_;
#pragma unroll
        for (int kc = 0; kc < 4; ++kc)
            qf[kc] = *(const bf16x8*)(qp + kc * 16 + hi * 8);
    }

    f32x16 acc0 = {}, acc1 = {}, acc2 = {}, acc3 = {};   // k2=0:{dt0,dt1}, k2=1:{dt0,dt1}
    float lsum = 0.f;

    const int srow = l >> 3, schk = l & 7;
    const __bf16* ksrc = Kb + ((size_t)b * J_ + wid * 8 + srow) * INNER_ + h * D_ + ((schk ^ srow) * 8);
    const __bf16* vsrc = Vt + ((size_t)bh * D_ + wid * 8 + srow) * J_ + ((schk ^ srow) * 8);

#define STAGE_T(bb, t) do { \
    _Pragma("unroll") \
    for (int c = 0; c < 2; ++c) { \
        __builtin_amdgcn_global_load_lds((const __attribute__((address_space(1))) void*)(ksrc + ((size_t)(t) * 64 + c * 32) * INNER_), \
            (__attribute__((address_space(3))) void*)(&sK[bb][(c * 4 + wid) * SEGE]), 16, 0, 0); \
        __builtin_amdgcn_global_load_lds((const __attribute__((address_space(1))) void*)(vsrc + (size_t)(c) * 32 * J_ + (t) * 64), \
            (__attribute__((address_space(3))) void*)(&sV[bb][(c * 4 + wid) * SEGE]), 16, 0, 0); \
    } } while (0)

    STAGE_T(0, 0);
    __syncthreads();

    for (int t = 0; t < J_ / 64; ++t) {
        const int bb = t & 1;
        if (t < J_ / 64 - 1) STAGE_T(bb ^ 1, t + 1);

        const __bf16* Ks = sK[bb];
        const __bf16* Vs = sV[bb];

#pragma unroll
        for (int jsub = 0; jsub < 2; ++jsub) {
            bf16x8 kf[4], vf[2][2];
            const int ksg = (jsub * 4 + (lq >> 3)) * SEGE + (lq & 7) * 64;
#pragma unroll
            for (int kc = 0; kc < 4; ++kc)
                kf[kc] = *(const bf16x8*)&Ks[ksg + (((kc * 2 + hi) ^ (lq & 7)) * 8)];
#pragma unroll
            for (int dt = 0; dt < 2; ++dt) {
                const int vsg = (dt * 4 + (lq >> 3)) * SEGE + (lq & 7) * 64;
#pragma unroll
                for (int k2 = 0; k2 < 2; ++k2)
                    vf[dt][k2] = *(const bf16x8*)&Vs[vsg + ((((jsub * 2 + k2) * 2 + hi) ^ (lq & 7)) * 8)];
            }

            f32x16 s = {};
            __builtin_amdgcn_s_setprio(1);
#pragma unroll
            for (int kc = 0; kc < 4; ++kc)
                s = __builtin_amdgcn_mfma_f32_32x32x16_bf16(kf[kc], qf[kc], s, 0, 0, 0);
            __builtin_amdgcn_s_setprio(0);

            float p[16];
#pragma unroll
            for (int r = 0; r < 16; ++r)
                p[r] = __builtin_amdgcn_exp2f(s[r]);
            {
                float t0 = (p[0] + p[1]) + (p[2] + p[3]);
                float t1 = (p[4] + p[5]) + (p[6] + p[7]);
                float t2 = (p[8] + p[9]) + (p[10] + p[11]);
                float t3 = (p[12] + p[13]) + (p[14] + p[15]);
                lsum += (t0 + t1) + (t2 + t3);
            }

#pragma unroll
            for (int k2 = 0; k2 < 2; ++k2) {
                unsigned a0 = pack2(p[k2 * 8 + 0], p[k2 * 8 + 1]);
                unsigned a1 = pack2(p[k2 * 8 + 2], p[k2 * 8 + 3]);
                unsigned b0 = pack2(p[k2 * 8 + 4], p[k2 * 8 + 5]);
                unsigned b1 = pack2(p[k2 * 8 + 6], p[k2 * 8 + 7]);
                uint2v r0 = __builtin_amdgcn_permlane32_swap(a0, b0, false, false);
                uint2v r1 = __builtin_amdgcn_permlane32_swap(a1, b1, false, false);
                union { unsigned u[4]; bf16x8 v; } pu;
                pu.u[0] = r0[0];
                pu.u[1] = r1[0];
                pu.u[2] = r0[1];
                pu.u[3] = r1[1];
                __builtin_amdgcn_s_setprio(1);
                if (k2 == 0) {
                    acc0 = __builtin_amdgcn_mfma_f32_32x32x16_bf16(vf[0][0], pu.v, acc0, 0, 0, 0);
                    acc1 = __builtin_amdgcn_mfma_f32_32x32x16_bf16(vf[1][0], pu.v, acc1, 0, 0, 0);
                } else {
                    acc2 = __builtin_amdgcn_mfma_f32_32x32x16_bf16(vf[0][1], pu.v, acc2, 0, 0, 0);
                    acc3 = __builtin_amdgcn_mfma_f32_32x32x16_bf16(vf[1][1], pu.v, acc3, 0, 0, 0);
                }
                __builtin_amdgcn_s_setprio(0);
            }
        }
        __syncthreads();
    }
#undef STAGE_T

    {
        float lt = lsum + __shfl_xor(lsum, 32);
        float inv = 1.f / lt;
        __bf16* op = Ob + ((size_t)b * N_ + qt * 128 + wid * 32 + lq) * INNER_ + h * D_;
        f32x16 am0 = acc0 + acc2;   // dt=0 chains merged (disjoint j sets)
        f32x16 am1 = acc1 + acc3;   // dt=1
#pragma unroll
        for (int g = 0; g < 4; ++g) {
            bf16x4 v4;
#pragma unroll
            for (int e = 0; e < 4; ++e) v4[e] = to_bf16(am0[g * 4 + e] * inv);
            *(bf16x4*)&op[g * 8 + hi * 4] = v4;
        }
#pragma unroll
        for (int g = 0; g < 4; ++g) {
            bf16x4 v4;
#pragma unroll
            for (int e = 0; e < 4; ++e) v4[e] = to_bf16(am1[g * 4 + e] * inv);
            *(bf16x4*)&op[32 + g * 8 + hi * 4] = v4;
        }
    }
}

// ---------------- host ----------------
extern "C" void kernel_launch(void* const* d_in, const int* in_sizes, int n_in,
                              void* d_out, int out_size, void* d_ws, size_t ws_size,
                              hipStream_t stream)
{
    const float* x   = (const float*)d_in[0];
    const float* ctx = (const float*)d_in[1];
    const float* Wq  = (const float*)d_in[2];
    const float* Wk  = (const float*)d_in[3];
    const float* Wv  = (const float*)d_in[4];
    const float* Wo  = (const float*)d_in[5];
    const float* bo  = (const float*)d_in[6];
    float* out = (float*)d_out;

    char* w = (char*)d_ws;
    auto take = [&](size_t bytes) { char* p = w; w += bytes; return p; };
    __bf16* xb  = (__bf16*)take((size_t)B_ * N_ * QD_ * 2);
    __bf16* cb  = (__bf16*)take((size_t)B_ * J_ * CD_ * 2);
    __bf16* wqt = (__bf16*)take((size_t)QD_ * INNER_ * 2);
    __bf16* wkt = (__bf16*)take((size_t)CD_ * INNER_ * 2);   // wkt+wvt adjacent
    __bf16* wvt = (__bf16*)take((size_t)CD_ * INNER_ * 2);
    __bf16* wot = (__bf16*)take((size_t)INNER_ * QD_ * 2);
    __bf16* Qb  = (__bf16*)take((size_t)B_ * N_ * INNER_ * 2);
    __bf16* Kb  = (__bf16*)take((size_t)B_ * J_ * INNER_ * 2);
    __bf16* Vt  = (__bf16*)take((size_t)B_ * J_ * INNER_ * 2);
    __bf16* Ob  = xb;

    const float SCALE_Q = 0.125f * 1.44269504088896f;

    aux_all<<<NCVT_BLK + 4096, 256, 0, stream>>>(x, ctx, xb, cb,
                                                 Wq, Wk, Wv, Wo,
                                                 wqt, wkt, wvt, wot, SCALE_Q);

    gemm_qkv<<<512, 512, 0, stream>>>(xb, wqt, Qb, cb, wkt, Kb, Vt);

    attn2<<<(N_ / 128) * H_ * B_, 256, 0, stream>>>(Qb, Kb, Vt, Ob);

    gemm_o<<<256, 512, 0, stream>>>(Ob, wot, out, bo);
}